// Round 20
// baseline (672.704 us; speedup 1.0000x reference)
//
#include <hip/hip_runtime.h>

#define T_SEQ 1024
#define C_DIM 1024
#define H_DIM 4096
#define M_ROWS 16384   // P*B*T = 2*8*1024
#define CHUNKS 16
#define CLEN 64        // T_SEQ / CHUNKS

typedef _Float16 f16x8 __attribute__((ext_vector_type(8)));
typedef _Float16 f16x4 __attribute__((ext_vector_type(4)));
typedef float    f32x4 __attribute__((ext_vector_type(4)));

#define AS1 __attribute__((address_space(1)))
#define AS3 __attribute__((address_space(3)))

__device__ __forceinline__ void gload_lds16(const void* g, void* l) {
  __builtin_amdgcn_global_load_lds((const AS1 void*)g, (AS3 void*)l, 16, 0, 0);
}

__device__ __forceinline__ float sigmoidf_(float x) {
  return 1.0f / (1.0f + __expf(-x));
}

// ---------------- fused weight f32 -> f16 (all 7 weights, one launch) --------
struct CvtArgs {
  const float* src[7];
  _Float16*    dst[7];
  int n4[7];       // elements/4 per source
  int start[8];    // block-range prefix
};

__global__ __launch_bounds__(256) void cvt_all_kernel(CvtArgs a) {
  const int bid = blockIdx.x;
  int s = 0;
#pragma unroll
  for (int j = 0; j < 7; ++j) s += (bid >= a.start[j + 1]) ? 1 : 0;
  const int i = (bid - a.start[s]) * 256 + threadIdx.x;
  if (i >= a.n4[s]) return;
  f32x4 v = reinterpret_cast<const f32x4*>(a.src[s])[i];
  f16x4 o;
  o[0] = (_Float16)v[0]; o[1] = (_Float16)v[1];
  o[2] = (_Float16)v[2]; o[3] = (_Float16)v[3];
  reinterpret_cast<f16x4*>(a.dst[s])[i] = o;
}

// ======== fused LayerNorm + time-shift mix (h never materialized) ========
template<int NMIX>
__global__ __launch_bounds__(512) void lnmix_kernel(const float* __restrict__ x,
    const float* __restrict__ g, const float* __restrict__ b,
    const float* __restrict__ mk, const float* __restrict__ mv,
    const float* __restrict__ mr,
    _Float16* __restrict__ xk, _Float16* __restrict__ xv,
    _Float16* __restrict__ xr) {
  const int wave = threadIdx.x >> 6;
  const int lane = threadIdx.x & 63;
  const int row  = blockIdx.x * 8 + wave;
  const int t    = row & (T_SEQ - 1);
  const int p    = row >> 13;
  const f32x4* x0 = reinterpret_cast<const f32x4*>(x + (size_t)row * C_DIM);
  const f32x4* x1 = reinterpret_cast<const f32x4*>(x + (size_t)(row - 1) * C_DIM);
  f32x4 vc[4], vp[4];
  float s0 = 0.f, q0 = 0.f, s1 = 0.f, q1 = 0.f;
#pragma unroll
  for (int i = 0; i < 4; ++i) {
    vc[i] = x0[i * 64 + lane];
#pragma unroll
    for (int j = 0; j < 4; ++j) { s0 += vc[i][j]; q0 += vc[i][j] * vc[i][j]; }
    if (t) {
      vp[i] = x1[i * 64 + lane];
#pragma unroll
      for (int j = 0; j < 4; ++j) { s1 += vp[i][j]; q1 += vp[i][j] * vp[i][j]; }
    }
  }
#pragma unroll
  for (int off = 32; off > 0; off >>= 1) {
    s0 += __shfl_xor(s0, off, 64);
    q0 += __shfl_xor(q0, off, 64);
    s1 += __shfl_xor(s1, off, 64);
    q1 += __shfl_xor(q1, off, 64);
  }
  const float mu0   = s0 * (1.0f / C_DIM);
  const float rstd0 = rsqrtf(q0 * (1.0f / C_DIM) - mu0 * mu0 + 1e-5f);
  const float mu1   = s1 * (1.0f / C_DIM);
  const float rstd1 = rsqrtf(q1 * (1.0f / C_DIM) - mu1 * mu1 + 1e-5f);
  const f32x4* g4  = reinterpret_cast<const f32x4*>(g);
  const f32x4* b4  = reinterpret_cast<const f32x4*>(b);
  const f32x4* mk4 = reinterpret_cast<const f32x4*>(mk + (size_t)p * C_DIM);
  const f32x4* mv4 = NMIX == 3 ? reinterpret_cast<const f32x4*>(mv + (size_t)p * C_DIM) : nullptr;
  const f32x4* mr4 = reinterpret_cast<const f32x4*>(mr + (size_t)p * C_DIM);
  f16x4* xk4 = reinterpret_cast<f16x4*>(xk) + (size_t)row * 256;
  f16x4* xv4 = NMIX == 3 ? reinterpret_cast<f16x4*>(xv) + (size_t)row * 256 : nullptr;
  f16x4* xr4 = reinterpret_cast<f16x4*>(xr) + (size_t)row * 256;
#pragma unroll
  for (int i = 0; i < 4; ++i) {
    const f32x4 gg = g4[i * 64 + lane];
    const f32x4 bb = b4[i * 64 + lane];
    const f32x4 ak = mk4[i * 64 + lane];
    const f32x4 ar = mr4[i * 64 + lane];
    f32x4 av;
    if (NMIX == 3) av = mv4[i * 64 + lane];
    f16x4 ok, ov, orr;
#pragma unroll
    for (int j = 0; j < 4; ++j) {
      const float hc = (vc[i][j] - mu0) * rstd0 * gg[j] + bb[j];
      const float hp = t ? ((vp[i][j] - mu1) * rstd1 * gg[j] + bb[j]) : 0.f;
      ok[j] = (_Float16)(hc * ak[j] + hp * (1.f - ak[j]));
      orr[j] = (_Float16)(hc * ar[j] + hp * (1.f - ar[j]));
      if (NMIX == 3) ov[j] = (_Float16)(hc * av[j] + hp * (1.f - av[j]));
    }
    xk4[i * 64 + lane] = ok;
    xr4[i * 64 + lane] = orr;
    if (NMIX == 3) xv4[i * 64 + lane] = ov;
  }
}

// ---------------- WKV parallel chunked scan, fused with a = sigmoid(r)*y -------
__global__ __launch_bounds__(1024, 1) void wkv_kernel(const _Float16* __restrict__ k,
    const _Float16* __restrict__ v, const _Float16* __restrict__ r,
    const float* __restrict__ td, const float* __restrict__ tf,
    _Float16* __restrict__ a_out) {
  __shared__ float sA[CHUNKS][64];
  __shared__ float sB[CHUNKS][64];
  __shared__ float sP[CHUNKS][64];
  const int tid   = threadIdx.x;
  const int chunk = tid >> 6;
  const int ch    = tid & 63;
  const int n     = blockIdx.x >> 4;     // 16 sequences
  const int cg    = blockIdx.x & 15;     // 16 channel groups of 64
  const int c     = cg * 64 + ch;
  const float w = -__expf(td[c]);
  const float u = tf[c];
  const size_t cbase = (size_t)n * T_SEQ * C_DIM + (size_t)chunk * CLEN * C_DIM + c;

  float aa = 0.f, bb = 0.f, pp = -1e38f;
  for (int s = 0; s < CLEN; ++s) {
    const size_t idx = cbase + (size_t)s * C_DIM;
    const float kk = (float)k[idx];
    const float vv = (float)v[idx];
    const float ww2 = w + pp;
    const float p2  = fmaxf(ww2, kk);
    const float e1b = __expf(ww2 - p2);
    const float e2b = __expf(kk - p2);
    aa = e1b * aa + e2b * vv;
    bb = e1b * bb + e2b;
    pp = p2;
  }
  sA[chunk][ch] = aa; sB[chunk][ch] = bb; sP[chunk][ch] = pp;
  __syncthreads();

  if (chunk == 0) {
    float pa = 0.f, pb = 0.f, ppr = -1e38f;
    const float wL = w * (float)CLEN;
    for (int j = 0; j < CHUNKS; ++j) {
      const float la = sA[j][ch], lb = sB[j][ch], lp = sP[j][ch];
      sA[j][ch] = pa; sB[j][ch] = pb; sP[j][ch] = ppr;
      const float dp = wL + ppr;
      const float np = fmaxf(dp, lp);
      const float e1 = __expf(dp - np);
      const float e2 = __expf(lp - np);
      pa  = e1 * pa + e2 * la;
      pb  = e1 * pb + e2 * lb;
      ppr = np;
    }
  }
  __syncthreads();

  aa = sA[chunk][ch]; bb = sB[chunk][ch]; pp = sP[chunk][ch];
  for (int s = 0; s < CLEN; ++s) {
    const size_t idx = cbase + (size_t)s * C_DIM;
    const float kk = (float)k[idx];
    const float vv = (float)v[idx];
    const float ww = u + kk;
    const float p  = fmaxf(pp, ww);
    const float e1 = __expf(pp - p);
    const float e2 = __expf(ww - p);
    const float yv = __fdividef(e1 * aa + e2 * vv, e1 * bb + e2);
    const float sr = sigmoidf_((float)r[idx]);
    a_out[idx] = (_Float16)(sr * yv);
    const float ww2 = w + pp;
    const float p2  = fmaxf(ww2, kk);
    const float e1b = __expf(ww2 - p2);
    const float e2b = __expf(kk - p2);
    aa = e1b * aa + e2b * vv;
    bb = e1b * bb + e2b;
    pp = p2;
  }
}

// ======== 128x128 GEMM, 256 threads, 64KB LDS -> 2 blocks/CU (R20) ========
// C[M,N] = A[M,K] * B[N,K]^T.  256 threads = 4 waves (2M x 2N), per-wave
// 64x64 output (acc 4x4 f32x4 = 64 VGPR), 16x16x32 MFMA, BK=64.
// R20 mechanism (m114): the R12-R19 family runs 1 block/CU, so every
// barrier/vmcnt stalls the whole CU. 64KB LDS + launch_bounds(256,2)
// (VGPR cap 256; acc 64 + operands ~64 + addr ~20 fits) gives 2 blocks/CU:
// when block A stalls, block B computes. Single compiler-scheduled region
// per tile (R17 body — correct, and now backed by cross-block TLP).
// Staging: operand = 128 rows x 64 halfs; 4 sweeps of 32 rows; source
// slot XOR (tid&7)^(row&7) (same bank structure as R16: 0 conflicts),
// linear LDS dest (rule 21), same XOR on ds_read.
// vmcnt LEDGER (8 loads/tile): stage t+1 -> 16 outstanding, vmcnt(8)
// forces tile t's 8. Overwrite of nb is barrier-separated from its
// readers (reads consumed before prior tile's closing barrier).
// EPI 0: f16; 1: f16(relu^2); 2: f32 acc+X; 3: f32 X + sigmoid(acc)*KV
#define BAR() __builtin_amdgcn_s_barrier()
#define WVN(n) do { asm volatile("s_waitcnt vmcnt(" #n ")" ::: "memory"); \
                    __builtin_amdgcn_sched_barrier(0); } while (0)
// stage one operand (128 rows x 64 halfs) in 4 sweeps of 32 rows
#define STAGEOP(op, SRCP, k0, bb) do { \
    _Pragma("unroll") \
    for (int s_ = 0; s_ < 4; ++s_) { \
      gload_lds16((SRCP) + (size_t)(s_ * 32) * K + (k0), \
                  &lds[bb][op][((size_t)(s_ * 32) << 6) + dbase]); \
    } } while (0)

template<int EPI>
__global__ __launch_bounds__(256, 2) void gemm_nt_128(
    const _Float16* __restrict__ A, const _Float16* __restrict__ B,
    void* __restrict__ Cv, const float* __restrict__ X,
    const _Float16* __restrict__ KV, int M, int N, int K,
    size_t strideA, size_t strideB, size_t strideCbytes) {
  __shared__ _Float16 lds[2][2][128 * 64];   // 64 KiB
  const int tid  = threadIdx.x;
  const int wave = tid >> 6;
  const int lane = tid & 63;
  const int wr   = wave >> 1;     // 0..1 (M half)
  const int wc   = wave & 1;      // 0..1 (N half)

  A  = A + (size_t)blockIdx.z * strideA;
  B  = B + (size_t)blockIdx.z * strideB;
  Cv = (void*)((char*)Cv + (size_t)blockIdx.z * strideCbytes);

  // XCD-bijective swizzle: XCD owns contiguous M chunk, n-fastest within.
  const unsigned nwx  = gridDim.x;        // N/128
  const unsigned pery = gridDim.y >> 3;   // m-tiles per XCD (128>>3 = 16)
  const unsigned id   = blockIdx.y * nwx + blockIdx.x;
  const unsigned xcd  = id & 7;
  const unsigned loc  = id >> 3;
  const size_t m0 = (size_t)(xcd * pery + loc / nwx) * 128;
  const size_t n0 = (size_t)(loc % nwx) * 128;

  // staging geometry: sweep = 32 rows x 64 halfs; thread -> row = tid>>3,
  // source 16B-slot XOR-swizzled; LDS dest wave-uniform base + lane*16B.
  const int srow  = tid >> 3;                       // 0..31
  const int scolh = ((tid & 7) ^ (srow & 7)) << 3;  // source-swizzled col (halfs)
  const size_t dbase = (size_t)(srow & ~7) << 6;    // wave-uniform (8 rows/wave)
  const _Float16* sA = A + (m0 + srow) * (size_t)K + scolh;
  const _Float16* sB = B + (n0 + srow) * (size_t)K + scolh;

  // fragment geometry (identical bank math to R16; measured 0 conflicts)
  const int frow  = lane & 15;
  const int fk    = (lane >> 4) << 3;
  const int fxorh = (frow & 7) << 3;

  f32x4 acc[4][4];
#pragma unroll
  for (int i = 0; i < 4; ++i)
#pragma unroll
    for (int j = 0; j < 4; ++j) acc[i][j] = (f32x4){0.f, 0.f, 0.f, 0.f};

  const int NT = K >> 6;
  // prologue: stage tile 0 -> buf 0 (8 loads)
  STAGEOP(0, sA, 0, 0);
  STAGEOP(1, sB, 0, 0);

  for (int t = 0; t < NT; ++t) {
    const int bi = t & 1;
    const int nb = bi ^ 1;
    const int k1 = (t + 1) << 6;
    if (t + 1 < NT) {
      STAGEOP(0, sA, k1, nb);
      STAGEOP(1, sB, k1, nb);
      WVN(8);           // tile t's 8 loads landed; t+1's 8 in flight
    } else {
      WVN(0);
    }
    BAR();
    // one compiler-scheduled region: 16 ds_reads + 32 MFMA
    f16x8 af[4][2], bf[4][2];
#pragma unroll
    for (int mf = 0; mf < 4; ++mf)
#pragma unroll
      for (int k_ = 0; k_ < 2; ++k_)
        af[mf][k_] = *reinterpret_cast<const f16x8*>(
            &lds[bi][0][((wr * 64 + mf * 16 + frow) << 6) +
                        (((k_ << 5) + fk) ^ fxorh)]);
#pragma unroll
    for (int nf = 0; nf < 4; ++nf)
#pragma unroll
      for (int k_ = 0; k_ < 2; ++k_)
        bf[nf][k_] = *reinterpret_cast<const f16x8*>(
            &lds[bi][1][((wc * 64 + nf * 16 + frow) << 6) +
                        (((k_ << 5) + fk) ^ fxorh)]);
#pragma unroll
    for (int k_ = 0; k_ < 2; ++k_)
#pragma unroll
      for (int mf = 0; mf < 4; ++mf)
#pragma unroll
        for (int nf = 0; nf < 4; ++nf)
          acc[mf][nf] = __builtin_amdgcn_mfma_f32_16x16x32_f16(
              af[mf][k_], bf[nf][k_], acc[mf][nf], 0, 0, 0);
    BAR();
  }

  // epilogue: C/D layout (16x16): col = lane&15, row = (lane>>4)*4 + reg
  const int ecol  = lane & 15;
  const int erow4 = (lane >> 4) * 4;
#pragma unroll
  for (int mf = 0; mf < 4; ++mf)
#pragma unroll
    for (int nf = 0; nf < 4; ++nf) {
      const size_t rbase = m0 + (size_t)(wr * 64 + mf * 16 + erow4);
      const size_t cc    = n0 + (size_t)(wc * 64 + nf * 16 + ecol);
#pragma unroll
      for (int r = 0; r < 4; ++r) {
        const float val = acc[mf][nf][r];
        const size_t off = (rbase + r) * (size_t)N + cc;
        if constexpr (EPI == 0) {
          ((_Float16*)Cv)[off] = (_Float16)val;
        } else if constexpr (EPI == 1) {
          const float tq = fmaxf(val, 0.f);
          ((_Float16*)Cv)[off] = (_Float16)(tq * tq);
        } else if constexpr (EPI == 2) {
          ((float*)Cv)[off] = val + X[off];
        } else {
          ((float*)Cv)[off] = X[off] + sigmoidf_(val) * (float)KV[off];
        }
      }
    }
}

extern "C" void kernel_launch(void* const* d_in, const int* in_sizes, int n_in,
                              void* d_out, int out_size, void* d_ws, size_t ws_size,
                              hipStream_t stream) {
  const float* x      = (const float*)d_in[0];
  const float* ln1_g  = (const float*)d_in[1];
  const float* ln1_b  = (const float*)d_in[2];
  const float* ln2_g  = (const float*)d_in[3];
  const float* ln2_b  = (const float*)d_in[4];
  const float* tdec   = (const float*)d_in[5];
  const float* tfirst = (const float*)d_in[6];
  const float* amk    = (const float*)d_in[7];
  const float* amv    = (const float*)d_in[8];
  const float* amr    = (const float*)d_in[9];
  const float* Wk     = (const float*)d_in[10];
  const float* Wv     = (const float*)d_in[11];
  const float* Wr     = (const float*)d_in[12];
  const float* Wo     = (const float*)d_in[13];
  const float* cmk    = (const float*)d_in[14];
  const float* cmr    = (const float*)d_in[15];
  const float* Wck    = (const float*)d_in[16];
  const float* Wcr    = (const float*)d_in[17];
  const float* Wcv    = (const float*)d_in[18];

  char* ws = (char*)d_ws;
  const size_t SZ = (size_t)M_ROWS * C_DIM * sizeof(_Float16);  // 32 MiB
  _Float16* B0 = (_Float16*)(ws + 0 * SZ);
  _Float16* B1 = (_Float16*)(ws + 1 * SZ);
  _Float16* B2 = (_Float16*)(ws + 2 * SZ);
  _Float16* B3 = (_Float16*)(ws + 3 * SZ);   // kk spans B3..B6 (128 MiB)
  _Float16* B4 = (_Float16*)(ws + 4 * SZ);
  _Float16* B5 = (_Float16*)(ws + 5 * SZ);
  _Float16* B6 = (_Float16*)(ws + 6 * SZ);
  _Float16* wWk  = (_Float16*)(ws + 7 * SZ);
  _Float16* wWv  = wWk  + (size_t)C_DIM * C_DIM;
  _Float16* wWr  = wWv  + (size_t)C_DIM * C_DIM;
  _Float16* wWo  = wWr  + (size_t)C_DIM * C_DIM;
  _Float16* wWcr = wWo  + (size_t)C_DIM * C_DIM;
  _Float16* wWck = wWcr + (size_t)C_DIM * C_DIM;
  _Float16* wWcv = wWck + (size_t)H_DIM * C_DIM;

  // fused weight cast: one launch for all 7 weights
  {
    CvtArgs a;
    const float* srcs[7] = {Wk, Wv, Wr, Wo, Wcr, Wck, Wcv};
    _Float16*    dsts[7] = {wWk, wWv, wWr, wWo, wWcr, wWck, wWcv};
    const size_t ns[7]   = {(size_t)C_DIM * C_DIM, (size_t)C_DIM * C_DIM,
                            (size_t)C_DIM * C_DIM, (size_t)C_DIM * C_DIM,
                            (size_t)C_DIM * C_DIM, (size_t)H_DIM * C_DIM,
                            (size_t)C_DIM * H_DIM};
    int st = 0;
    for (int j = 0; j < 7; ++j) {
      a.src[j] = srcs[j]; a.dst[j] = dsts[j];
      a.n4[j] = (int)(ns[j] / 4);
      a.start[j] = st;
      st += (a.n4[j] + 255) / 256;
    }
    a.start[7] = st;
    cvt_all_kernel<<<dim3(st), dim3(256), 0, stream>>>(a);
  }

  const dim3 gblk(256);
  const dim3 gLN(M_ROWS / 8);                     // lnmix: 8 rows/block
  const dim3 gN1(C_DIM / 128, M_ROWS / 128);      // (8, 128)
  const dim3 gKVR(C_DIM / 128, M_ROWS / 128, 3);  // batched k,v,r
  const dim3 gN4(H_DIM / 128, M_ROWS / 128);      // (32, 128)

  // --- TimeMix ---
  lnmix_kernel<3><<<gLN, dim3(512), 0, stream>>>(x, ln1_g, ln1_b, amk, amv, amr,
                                                 B1, B2, B3);
  // batched k,v,r projections: A = {B1,B2,B3}, B = {wWk,wWv,wWr}, C = {B4,B5,B6}
  gemm_nt_128<0><<<gKVR, gblk, 0, stream>>>(B1, wWk, B4, nullptr, nullptr,
      M_ROWS, C_DIM, C_DIM,
      (size_t)M_ROWS * C_DIM, (size_t)C_DIM * C_DIM,
      (size_t)M_ROWS * C_DIM * sizeof(_Float16));
  wkv_kernel<<<dim3(256), dim3(1024), 0, stream>>>(B4, B5, B6, tdec, tfirst, B1);
  gemm_nt_128<2><<<gN1, gblk, 0, stream>>>(B1, wWo, d_out, x, nullptr,
      M_ROWS, C_DIM, C_DIM, 0, 0, 0);

  // --- ChannelMix ---
  lnmix_kernel<2><<<gLN, dim3(512), 0, stream>>>((const float*)d_out, ln2_g, ln2_b,
                                                 cmk, nullptr, cmr, B1, nullptr, B2);
  gemm_nt_128<1><<<gN4, gblk, 0, stream>>>(B1, wWck, B3, nullptr, nullptr,
      M_ROWS, H_DIM, C_DIM, 0, 0, 0);
  gemm_nt_128<0><<<gN1, gblk, 0, stream>>>(B3, wWcv, B1, nullptr, nullptr,
      M_ROWS, C_DIM, H_DIM, 0, 0, 0);
  gemm_nt_128<3><<<gN1, gblk, 0, stream>>>(B2, wWcr, d_out, (const float*)d_out, B1,
      M_ROWS, C_DIM, C_DIM, 0, 0, 0);
}

// Round 21
// 605.318 us; speedup vs baseline: 1.1113x; 1.1113x over previous
//
#include <hip/hip_runtime.h>

#define T_SEQ 1024
#define C_DIM 1024
#define H_DIM 4096
#define M_ROWS 16384   // P*B*T = 2*8*1024
#define CHUNKS 16
#define CLEN 64        // T_SEQ / CHUNKS

typedef _Float16 f16x8 __attribute__((ext_vector_type(8)));
typedef _Float16 f16x4 __attribute__((ext_vector_type(4)));
typedef float    f32x4 __attribute__((ext_vector_type(4)));

#define AS1 __attribute__((address_space(1)))
#define AS3 __attribute__((address_space(3)))

__device__ __forceinline__ void gload_lds16(const void* g, void* l) {
  __builtin_amdgcn_global_load_lds((const AS1 void*)g, (AS3 void*)l, 16, 0, 0);
}

__device__ __forceinline__ float sigmoidf_(float x) {
  return 1.0f / (1.0f + __expf(-x));
}

// ---------------- fused weight f32 -> f16 (all 7 weights, one launch) --------
struct CvtArgs {
  const float* src[7];
  _Float16*    dst[7];
  int n4[7];       // elements/4 per source
  int start[8];    // block-range prefix
};

__global__ __launch_bounds__(256) void cvt_all_kernel(CvtArgs a) {
  const int bid = blockIdx.x;
  int s = 0;
#pragma unroll
  for (int j = 0; j < 7; ++j) s += (bid >= a.start[j + 1]) ? 1 : 0;
  const int i = (bid - a.start[s]) * 256 + threadIdx.x;
  if (i >= a.n4[s]) return;
  f32x4 v = reinterpret_cast<const f32x4*>(a.src[s])[i];
  f16x4 o;
  o[0] = (_Float16)v[0]; o[1] = (_Float16)v[1];
  o[2] = (_Float16)v[2]; o[3] = (_Float16)v[3];
  reinterpret_cast<f16x4*>(a.dst[s])[i] = o;
}

// ======== fused LayerNorm + time-shift mix (h never materialized) ========
template<int NMIX>
__global__ __launch_bounds__(512) void lnmix_kernel(const float* __restrict__ x,
    const float* __restrict__ g, const float* __restrict__ b,
    const float* __restrict__ mk, const float* __restrict__ mv,
    const float* __restrict__ mr,
    _Float16* __restrict__ xk, _Float16* __restrict__ xv,
    _Float16* __restrict__ xr) {
  const int wave = threadIdx.x >> 6;
  const int lane = threadIdx.x & 63;
  const int row  = blockIdx.x * 8 + wave;
  const int t    = row & (T_SEQ - 1);
  const int p    = row >> 13;
  const f32x4* x0 = reinterpret_cast<const f32x4*>(x + (size_t)row * C_DIM);
  const f32x4* x1 = reinterpret_cast<const f32x4*>(x + (size_t)(row - 1) * C_DIM);
  f32x4 vc[4], vp[4];
  float s0 = 0.f, q0 = 0.f, s1 = 0.f, q1 = 0.f;
#pragma unroll
  for (int i = 0; i < 4; ++i) {
    vc[i] = x0[i * 64 + lane];
#pragma unroll
    for (int j = 0; j < 4; ++j) { s0 += vc[i][j]; q0 += vc[i][j] * vc[i][j]; }
    if (t) {
      vp[i] = x1[i * 64 + lane];
#pragma unroll
      for (int j = 0; j < 4; ++j) { s1 += vp[i][j]; q1 += vp[i][j] * vp[i][j]; }
    }
  }
#pragma unroll
  for (int off = 32; off > 0; off >>= 1) {
    s0 += __shfl_xor(s0, off, 64);
    q0 += __shfl_xor(q0, off, 64);
    s1 += __shfl_xor(s1, off, 64);
    q1 += __shfl_xor(q1, off, 64);
  }
  const float mu0   = s0 * (1.0f / C_DIM);
  const float rstd0 = rsqrtf(q0 * (1.0f / C_DIM) - mu0 * mu0 + 1e-5f);
  const float mu1   = s1 * (1.0f / C_DIM);
  const float rstd1 = rsqrtf(q1 * (1.0f / C_DIM) - mu1 * mu1 + 1e-5f);
  const f32x4* g4  = reinterpret_cast<const f32x4*>(g);
  const f32x4* b4  = reinterpret_cast<const f32x4*>(b);
  const f32x4* mk4 = reinterpret_cast<const f32x4*>(mk + (size_t)p * C_DIM);
  const f32x4* mv4 = NMIX == 3 ? reinterpret_cast<const f32x4*>(mv + (size_t)p * C_DIM) : nullptr;
  const f32x4* mr4 = reinterpret_cast<const f32x4*>(mr + (size_t)p * C_DIM);
  f16x4* xk4 = reinterpret_cast<f16x4*>(xk) + (size_t)row * 256;
  f16x4* xv4 = NMIX == 3 ? reinterpret_cast<f16x4*>(xv) + (size_t)row * 256 : nullptr;
  f16x4* xr4 = reinterpret_cast<f16x4*>(xr) + (size_t)row * 256;
#pragma unroll
  for (int i = 0; i < 4; ++i) {
    const f32x4 gg = g4[i * 64 + lane];
    const f32x4 bb = b4[i * 64 + lane];
    const f32x4 ak = mk4[i * 64 + lane];
    const f32x4 ar = mr4[i * 64 + lane];
    f32x4 av;
    if (NMIX == 3) av = mv4[i * 64 + lane];
    f16x4 ok, ov, orr;
#pragma unroll
    for (int j = 0; j < 4; ++j) {
      const float hc = (vc[i][j] - mu0) * rstd0 * gg[j] + bb[j];
      const float hp = t ? ((vp[i][j] - mu1) * rstd1 * gg[j] + bb[j]) : 0.f;
      ok[j] = (_Float16)(hc * ak[j] + hp * (1.f - ak[j]));
      orr[j] = (_Float16)(hc * ar[j] + hp * (1.f - ar[j]));
      if (NMIX == 3) ov[j] = (_Float16)(hc * av[j] + hp * (1.f - av[j]));
    }
    xk4[i * 64 + lane] = ok;
    xr4[i * 64 + lane] = orr;
    if (NMIX == 3) xv4[i * 64 + lane] = ov;
  }
}

// ---------------- WKV parallel chunked scan, fused with a = sigmoid(r)*y -------
__global__ __launch_bounds__(1024, 1) void wkv_kernel(const _Float16* __restrict__ k,
    const _Float16* __restrict__ v, const _Float16* __restrict__ r,
    const float* __restrict__ td, const float* __restrict__ tf,
    _Float16* __restrict__ a_out) {
  __shared__ float sA[CHUNKS][64];
  __shared__ float sB[CHUNKS][64];
  __shared__ float sP[CHUNKS][64];
  const int tid   = threadIdx.x;
  const int chunk = tid >> 6;
  const int ch    = tid & 63;
  const int n     = blockIdx.x >> 4;     // 16 sequences
  const int cg    = blockIdx.x & 15;     // 16 channel groups of 64
  const int c     = cg * 64 + ch;
  const float w = -__expf(td[c]);
  const float u = tf[c];
  const size_t cbase = (size_t)n * T_SEQ * C_DIM + (size_t)chunk * CLEN * C_DIM + c;

  float aa = 0.f, bb = 0.f, pp = -1e38f;
  for (int s = 0; s < CLEN; ++s) {
    const size_t idx = cbase + (size_t)s * C_DIM;
    const float kk = (float)k[idx];
    const float vv = (float)v[idx];
    const float ww2 = w + pp;
    const float p2  = fmaxf(ww2, kk);
    const float e1b = __expf(ww2 - p2);
    const float e2b = __expf(kk - p2);
    aa = e1b * aa + e2b * vv;
    bb = e1b * bb + e2b;
    pp = p2;
  }
  sA[chunk][ch] = aa; sB[chunk][ch] = bb; sP[chunk][ch] = pp;
  __syncthreads();

  if (chunk == 0) {
    float pa = 0.f, pb = 0.f, ppr = -1e38f;
    const float wL = w * (float)CLEN;
    for (int j = 0; j < CHUNKS; ++j) {
      const float la = sA[j][ch], lb = sB[j][ch], lp = sP[j][ch];
      sA[j][ch] = pa; sB[j][ch] = pb; sP[j][ch] = ppr;
      const float dp = wL + ppr;
      const float np = fmaxf(dp, lp);
      const float e1 = __expf(dp - np);
      const float e2 = __expf(lp - np);
      pa  = e1 * pa + e2 * la;
      pb  = e1 * pb + e2 * lb;
      ppr = np;
    }
  }
  __syncthreads();

  aa = sA[chunk][ch]; bb = sB[chunk][ch]; pp = sP[chunk][ch];
  for (int s = 0; s < CLEN; ++s) {
    const size_t idx = cbase + (size_t)s * C_DIM;
    const float kk = (float)k[idx];
    const float vv = (float)v[idx];
    const float ww = u + kk;
    const float p  = fmaxf(pp, ww);
    const float e1 = __expf(pp - p);
    const float e2 = __expf(ww - p);
    const float yv = __fdividef(e1 * aa + e2 * vv, e1 * bb + e2);
    const float sr = sigmoidf_((float)r[idx]);
    a_out[idx] = (_Float16)(sr * yv);
    const float ww2 = w + pp;
    const float p2  = fmaxf(ww2, kk);
    const float e1b = __expf(ww2 - p2);
    const float e2b = __expf(kk - p2);
    aa = e1b * aa + e2b * vv;
    bb = e1b * bb + e2b;
    pp = p2;
  }
}

// ============ 256x256 GEMM, R16 KEEPER: 4-phase, no order-pinning ============
// C[M,N] = A[M,K] * B[N,K]^T.  512 threads = 8 waves (2M x 4N), per-wave
// 128x64 output, 16x16x32 MFMA, BK=64, dbuf LDS [2][2][256*64] (row-split
// half-tiles H0=Ah0, H1=Bh0, H2=Bh1, H3=Ah1; zero measured bank conflicts).
// FINAL config — design space bracketed over R5-R20:
//   * 7 schedule variants with manual lgkmcnt + sched_barrier(0) pinning:
//     all 38% MfmaUtil (the pinning WAS the serializer, m141);
//   * R16 (this): remove pinning -> 45.3%, Wck 136us, total 606-608us (x2);
//   * R17 2-barrier collapse: -2%;  R14 fat waves: occupancy halved;
//   * R15 32x32 MFMA: bank conflicts structural at 64-half rows;
//   * R18 BK=32 @ 4w/SIMD: acc 128 VGPR > cap -> full spill;
//   * R20 128^2 tile @ 2 blocks/CU: FETCH x3.5 -> HBM-bound, -10%.
// vmcnt LEDGER (LOADS, 2/STAGE): prologue 12 loads, vmcnt(4) forces T0,
// keeps H0,H1(T1). Tile t: P0 stages H2(t+1)->nb, P1 H3(t+1)->nb,
// P2 H0(t+2)->bi, P3 H1(t+2)->bi then vmcnt(4) forces ALL of t+1.
// Cross-wave write-after-read: every region's values are in registers
// before the barrier preceding its overwrite.
// EPI 0: f16; 1: f16(relu^2); 2: f32 acc+X; 3: f32 X + sigmoid(acc)*KV
#define BAR() __builtin_amdgcn_s_barrier()
#define WVN(n) do { asm volatile("s_waitcnt vmcnt(" #n ")" ::: "memory"); \
                    __builtin_amdgcn_sched_barrier(0); } while (0)
#define STAGE(op, SRC, row0, k0, bb) do { \
    _Pragma("unroll") \
    for (int c_ = 0; c_ < 2; ++c_) { \
      gload_lds16((SRC) + (size_t)((row0) + c_ * 64) * K + (k0), \
                  &lds[bb][op][((size_t)((row0) + c_ * 64) << 6) + dbase]); \
    } } while (0)
#define RD_AH(dst, mh) do { \
    _Pragma("unroll") for (int i_ = 0; i_ < 4; ++i_) \
    _Pragma("unroll") for (int k_ = 0; k_ < 2; ++k_) \
      dst[i_][k_] = *reinterpret_cast<const f16x8*>( \
        &lds[bi][0][((wr * 128 + (mh) * 64 + i_ * 16 + frow) << 6) + \
                    (((k_ << 5) + fk) ^ fxorh)]); \
  } while (0)
#define RD_BH(dst, nh) do { \
    _Pragma("unroll") for (int j_ = 0; j_ < 2; ++j_) \
    _Pragma("unroll") for (int k_ = 0; k_ < 2; ++k_) \
      dst[j_][k_] = *reinterpret_cast<const f16x8*>( \
        &lds[bi][1][((wcn * 64 + (nh) * 32 + j_ * 16 + frow) << 6) + \
                    (((k_ << 5) + fk) ^ fxorh)]); \
  } while (0)
#define MM16(asrc, bsrc, mh, nh) do { \
    _Pragma("unroll") for (int k_ = 0; k_ < 2; ++k_) \
    _Pragma("unroll") for (int i_ = 0; i_ < 4; ++i_) \
    _Pragma("unroll") for (int j_ = 0; j_ < 2; ++j_) \
      acc[(mh) * 4 + i_][(nh) * 2 + j_] = __builtin_amdgcn_mfma_f32_16x16x32_f16( \
        asrc[i_][k_], bsrc[j_][k_], acc[(mh) * 4 + i_][(nh) * 2 + j_], 0, 0, 0); \
  } while (0)

template<int EPI>
__global__ __launch_bounds__(512, 2) void gemm_nt_256(
    const _Float16* __restrict__ A, const _Float16* __restrict__ B,
    void* __restrict__ Cv, const float* __restrict__ X,
    const _Float16* __restrict__ KV, int M, int N, int K,
    size_t strideA, size_t strideB, size_t strideCbytes) {
  __shared__ _Float16 lds[2][2][256 * 64];
  const int tid  = threadIdx.x;
  const int wave = tid >> 6;
  const int lane = tid & 63;
  const int wr   = wave >> 2;     // 0..1
  const int wcn  = wave & 3;      // 0..3

  A  = A + (size_t)blockIdx.z * strideA;
  B  = B + (size_t)blockIdx.z * strideB;
  Cv = (void*)((char*)Cv + (size_t)blockIdx.z * strideCbytes);

  // XCD-bijective swizzle: XCD owns contiguous M chunk, n-fastest within.
  const unsigned nwx  = gridDim.x;        // N/256
  const unsigned pery = gridDim.y >> 3;   // m-tiles per XCD
  const unsigned id   = blockIdx.y * nwx + blockIdx.x;
  const unsigned xcd  = id & 7;
  const unsigned loc  = id >> 3;
  const size_t m0 = (size_t)(xcd * pery + loc / nwx) * 256;
  const size_t n0 = (size_t)(loc % nwx) * 256;

  // staging geometry: half-tile = 128 rows x 64 halfs; 2 gload_lds/thread;
  // LDS dest wave-uniform base + lane*16B (linear), T2 swizzle via source.
  const int srow  = tid >> 3;                       // 0..63
  const int scolh = ((tid & 7) ^ (srow & 7)) << 3;  // source-swizzled col (halfs)
  const size_t dbase = (size_t)(srow & ~7) << 6;    // wave-uniform
  const _Float16* sA = A + (m0 + srow) * (size_t)K + scolh;
  const _Float16* sB = B + (n0 + srow) * (size_t)K + scolh;

  // fragment geometry
  const int frow  = lane & 15;
  const int fk    = (lane >> 4) << 3;
  const int fxorh = (frow & 7) << 3;

  f32x4 acc[8][4];
#pragma unroll
  for (int i = 0; i < 8; ++i)
#pragma unroll
    for (int j = 0; j < 4; ++j) acc[i][j] = (f32x4){0.f, 0.f, 0.f, 0.f};

  const int NT = K >> 6;
  // prologue: H0-H3(T0) -> buf0, H0,H1(T1) -> buf1; vmcnt(4) forces T0.
  STAGE(0, sA, 0,   0, 0);
  STAGE(1, sB, 0,   0, 0);
  STAGE(1, sB, 128, 0, 0);
  STAGE(0, sA, 128, 0, 0);
  if (NT > 1) {
    STAGE(0, sA, 0, 64, 1);
    STAGE(1, sB, 0, 64, 1);
    WVN(4);
  } else {
    WVN(0);
  }
  BAR();

  for (int t = 0; t < NT; ++t) {
    const int bi = t & 1;
    const int nb = bi ^ 1;
    const int k1 = (t + 1) << 6;
    const int k2 = (t + 2) << 6;
    const bool s1 = (t + 1) < NT;
    const bool s2 = (t + 2) < NT;
    f16x8 a0[4][2], a1[4][2], b0[2][2], b1[2][2];
    // ---- P0: Q(0,0) ----
    RD_AH(a0, 0); RD_BH(b0, 0);
    if (s1) STAGE(1, sB, 128, k1, nb);   // H2(t+1) = Bh1 -> nb
    BAR();
    MM16(a0, b0, 0, 0);
    BAR();
    // ---- P1: Q(0,1) ----
    RD_BH(b1, 1);
    if (s1) STAGE(0, sA, 128, k1, nb);   // H3(t+1) = Ah1 -> nb
    BAR();
    MM16(a0, b1, 0, 1);
    BAR();
    // ---- P2: Q(1,0) ----
    RD_AH(a1, 1);
    if (s2) STAGE(0, sA, 0, k2, bi);     // H0(t+2) = Ah0 -> bi
    BAR();
    MM16(a1, b0, 1, 0);
    BAR();
    // ---- P3: Q(1,1); end-of-tile vmcnt gate ----
    if (s2) {
      STAGE(1, sB, 0, k2, bi);           // H1(t+2) = Bh0 -> bi
      WVN(4);                            // forces ALL of tile t+1
    } else {
      WVN(0);
    }
    BAR();
    MM16(a1, b1, 1, 1);
    BAR();
  }

  // epilogue: C/D layout (16x16): col = lane&15, row = (lane>>4)*4 + reg
  const int ecol  = lane & 15;
  const int erow4 = (lane >> 4) * 4;
#pragma unroll
  for (int mf = 0; mf < 8; ++mf)
#pragma unroll
    for (int nf = 0; nf < 4; ++nf) {
      const size_t rbase = m0 + (size_t)(wr * 128 + mf * 16 + erow4);
      const size_t cc    = n0 + (size_t)(wcn * 64 + nf * 16 + ecol);
#pragma unroll
      for (int r = 0; r < 4; ++r) {
        const float val = acc[mf][nf][r];
        const size_t off = (rbase + r) * (size_t)N + cc;
        if constexpr (EPI == 0) {
          ((_Float16*)Cv)[off] = (_Float16)val;
        } else if constexpr (EPI == 1) {
          const float tq = fmaxf(val, 0.f);
          ((_Float16*)Cv)[off] = (_Float16)(tq * tq);
        } else if constexpr (EPI == 2) {
          ((float*)Cv)[off] = val + X[off];
        } else {
          ((float*)Cv)[off] = X[off] + sigmoidf_(val) * (float)KV[off];
        }
      }
    }
}

extern "C" void kernel_launch(void* const* d_in, const int* in_sizes, int n_in,
                              void* d_out, int out_size, void* d_ws, size_t ws_size,
                              hipStream_t stream) {
  const float* x      = (const float*)d_in[0];
  const float* ln1_g  = (const float*)d_in[1];
  const float* ln1_b  = (const float*)d_in[2];
  const float* ln2_g  = (const float*)d_in[3];
  const float* ln2_b  = (const float*)d_in[4];
  const float* tdec   = (const float*)d_in[5];
  const float* tfirst = (const float*)d_in[6];
  const float* amk    = (const float*)d_in[7];
  const float* amv    = (const float*)d_in[8];
  const float* amr    = (const float*)d_in[9];
  const float* Wk     = (const float*)d_in[10];
  const float* Wv     = (const float*)d_in[11];
  const float* Wr     = (const float*)d_in[12];
  const float* Wo     = (const float*)d_in[13];
  const float* cmk    = (const float*)d_in[14];
  const float* cmr    = (const float*)d_in[15];
  const float* Wck    = (const float*)d_in[16];
  const float* Wcr    = (const float*)d_in[17];
  const float* Wcv    = (const float*)d_in[18];

  char* ws = (char*)d_ws;
  const size_t SZ = (size_t)M_ROWS * C_DIM * sizeof(_Float16);  // 32 MiB
  _Float16* B0 = (_Float16*)(ws + 0 * SZ);
  _Float16* B1 = (_Float16*)(ws + 1 * SZ);
  _Float16* B2 = (_Float16*)(ws + 2 * SZ);
  _Float16* B3 = (_Float16*)(ws + 3 * SZ);   // kk spans B3..B6 (128 MiB)
  _Float16* B4 = (_Float16*)(ws + 4 * SZ);
  _Float16* B5 = (_Float16*)(ws + 5 * SZ);
  _Float16* B6 = (_Float16*)(ws + 6 * SZ);
  _Float16* wWk  = (_Float16*)(ws + 7 * SZ);
  _Float16* wWv  = wWk  + (size_t)C_DIM * C_DIM;
  _Float16* wWr  = wWv  + (size_t)C_DIM * C_DIM;
  _Float16* wWo  = wWr  + (size_t)C_DIM * C_DIM;
  _Float16* wWcr = wWo  + (size_t)C_DIM * C_DIM;
  _Float16* wWck = wWcr + (size_t)C_DIM * C_DIM;
  _Float16* wWcv = wWck + (size_t)H_DIM * C_DIM;

  // fused weight cast: one launch for all 7 weights
  {
    CvtArgs a;
    const float* srcs[7] = {Wk, Wv, Wr, Wo, Wcr, Wck, Wcv};
    _Float16*    dsts[7] = {wWk, wWv, wWr, wWo, wWcr, wWck, wWcv};
    const size_t ns[7]   = {(size_t)C_DIM * C_DIM, (size_t)C_DIM * C_DIM,
                            (size_t)C_DIM * C_DIM, (size_t)C_DIM * C_DIM,
                            (size_t)C_DIM * C_DIM, (size_t)H_DIM * C_DIM,
                            (size_t)C_DIM * H_DIM};
    int st = 0;
    for (int j = 0; j < 7; ++j) {
      a.src[j] = srcs[j]; a.dst[j] = dsts[j];
      a.n4[j] = (int)(ns[j] / 4);
      a.start[j] = st;
      st += (a.n4[j] + 255) / 256;
    }
    a.start[7] = st;
    cvt_all_kernel<<<dim3(st), dim3(256), 0, stream>>>(a);
  }

  const dim3 gblk(512);
  const dim3 gLN(M_ROWS / 8);                     // lnmix: 8 rows/block
  const dim3 gN1(C_DIM / 256, M_ROWS / 256);      // (4, 64)
  const dim3 gKVR(C_DIM / 256, M_ROWS / 256, 3);  // batched k,v,r
  const dim3 gN4(H_DIM / 256, M_ROWS / 256);      // (16, 64)

  // --- TimeMix ---
  lnmix_kernel<3><<<gLN, dim3(512), 0, stream>>>(x, ln1_g, ln1_b, amk, amv, amr,
                                                 B1, B2, B3);
  // batched k,v,r projections: A = {B1,B2,B3}, B = {wWk,wWv,wWr}, C = {B4,B5,B6}
  gemm_nt_256<0><<<gKVR, gblk, 0, stream>>>(B1, wWk, B4, nullptr, nullptr,
      M_ROWS, C_DIM, C_DIM,
      (size_t)M_ROWS * C_DIM, (size_t)C_DIM * C_DIM,
      (size_t)M_ROWS * C_DIM * sizeof(_Float16));
  wkv_kernel<<<dim3(256), dim3(1024), 0, stream>>>(B4, B5, B6, tdec, tfirst, B1);
  gemm_nt_256<2><<<gN1, gblk, 0, stream>>>(B1, wWo, d_out, x, nullptr,
      M_ROWS, C_DIM, C_DIM, 0, 0, 0);

  // --- ChannelMix ---
  lnmix_kernel<2><<<gLN, dim3(512), 0, stream>>>((const float*)d_out, ln2_g, ln2_b,
                                                 cmk, nullptr, cmr, B1, nullptr, B2);
  gemm_nt_256<1><<<gN4, gblk, 0, stream>>>(B1, wWck, B3, nullptr, nullptr,
      M_ROWS, H_DIM, C_DIM, 0, 0, 0);
  gemm_nt_256<0><<<gN1, gblk, 0, stream>>>(B3, wWcv, B1, nullptr, nullptr,
      M_ROWS, C_DIM, H_DIM, 0, 0, 0);
  gemm_nt_256<3><<<gN1, gblk, 0, stream>>>(B2, wWcr, d_out, (const float*)d_out, B1,
      M_ROWS, C_DIM, C_DIM, 0, 0, 0);
}